// Round 1
// baseline (1139.735 us; speedup 1.0000x reference)
//
#include <hip/hip_runtime.h>
#include <cfloat>
#include <climits>
#include <cmath>

// Problem: A (N,1,2) f32 -> A_I = A[:,0,bag_label]; top-8 idx (desc) + bottom-8 idx (asc);
// gather h rows (N,512); logits = softmax(h[idx] @ W + b); out = [labels(16) as f32, logits(16,2)].
// jax.lax.top_k tie-break: equal values -> lower index first. Replicated exactly below.

#define NB 256   // pass-1 blocks (also = sources merged in pass 2, must be <= 256)
#define NT 256   // threads per block
#define K  8

__device__ __forceinline__ bool top_better(float v1, int i1, float v2, int i2) {
    return (v1 > v2) || (v1 == v2 && i1 < i2);
}
__device__ __forceinline__ bool bot_better(float v1, int i1, float v2, int i2) {
    return (v1 < v2) || (v1 == v2 && i1 < i2);
}

// ---------------- Pass 1: per-block top-8 / bottom-8 ----------------
__global__ __launch_bounds__(NT) void topk_pass1(const float2* __restrict__ A2,
                                                 const int* __restrict__ bag_label,
                                                 int n,
                                                 float* __restrict__ ws_v,
                                                 int* __restrict__ ws_i) {
    const int tid = threadIdx.x;
    const int gid = blockIdx.x * NT + tid;
    const int stride = gridDim.x * NT;
    const int lbl = bag_label[0];

    // register-resident sorted lists (constant indices only -> stays in VGPRs)
    float tv[K], bv[K];
    int   ti[K], bi[K];
#pragma unroll
    for (int k = 0; k < K; ++k) { tv[k] = -FLT_MAX; ti[k] = INT_MAX; bv[k] = FLT_MAX; bi[k] = INT_MAX; }

    for (int i = gid; i < n; i += stride) {
        float2 a = A2[i];
        float v = lbl ? a.y : a.x;
        // top-8 insert (descending)
        if (top_better(v, i, tv[K-1], ti[K-1])) {
#pragma unroll
            for (int p = K-1; p >= 1; --p) {
                if (top_better(v, i, tv[p], ti[p])) {
                    bool c1 = top_better(v, i, tv[p-1], ti[p-1]);
                    tv[p] = c1 ? tv[p-1] : v;
                    ti[p] = c1 ? ti[p-1] : i;
                }
            }
            if (top_better(v, i, tv[0], ti[0])) { tv[0] = v; ti[0] = i; }
        }
        // bottom-8 insert (ascending)
        if (bot_better(v, i, bv[K-1], bi[K-1])) {
#pragma unroll
            for (int p = K-1; p >= 1; --p) {
                if (bot_better(v, i, bv[p], bi[p])) {
                    bool c1 = bot_better(v, i, bv[p-1], bi[p-1]);
                    bv[p] = c1 ? bv[p-1] : v;
                    bi[p] = c1 ? bi[p-1] : i;
                }
            }
            if (bot_better(v, i, bv[0], bi[0])) { bv[0] = v; bi[0] = i; }
        }
    }

    __shared__ float cv[NT * K];
    __shared__ int   ci[NT * K];
    __shared__ float rv[NT];
    __shared__ int   ri[NT];

    // ---- top phase: heads-of-sorted-lists argmax, 8 rounds ----
#pragma unroll
    for (int k = 0; k < K; ++k) { cv[tid*K + k] = tv[k]; ci[tid*K + k] = ti[k]; }
    __syncthreads();
    int ptr = 0;
    for (int r = 0; r < K; ++r) {
        float hv = cv[tid*K + ptr];
        int   hi = ci[tid*K + ptr];
        rv[tid] = hv; ri[tid] = hi;
        __syncthreads();
        for (int s = NT/2; s > 0; s >>= 1) {
            if (tid < s && top_better(rv[tid+s], ri[tid+s], rv[tid], ri[tid])) {
                rv[tid] = rv[tid+s]; ri[tid] = ri[tid+s];
            }
            __syncthreads();
        }
        if (tid == 0) { ws_v[blockIdx.x*16 + r] = rv[0]; ws_i[blockIdx.x*16 + r] = ri[0]; }
        if (hv == rv[0] && hi == ri[0]) ptr++;   // unique (v,i): exactly one advances
        __syncthreads();
    }

    // ---- bottom phase ----
#pragma unroll
    for (int k = 0; k < K; ++k) { cv[tid*K + k] = bv[k]; ci[tid*K + k] = bi[k]; }
    __syncthreads();
    ptr = 0;
    for (int r = 0; r < K; ++r) {
        float hv = cv[tid*K + ptr];
        int   hi = ci[tid*K + ptr];
        rv[tid] = hv; ri[tid] = hi;
        __syncthreads();
        for (int s = NT/2; s > 0; s >>= 1) {
            if (tid < s && bot_better(rv[tid+s], ri[tid+s], rv[tid], ri[tid])) {
                rv[tid] = rv[tid+s]; ri[tid] = ri[tid+s];
            }
            __syncthreads();
        }
        if (tid == 0) { ws_v[blockIdx.x*16 + 8 + r] = rv[0]; ws_i[blockIdx.x*16 + 8 + r] = ri[0]; }
        if (hv == rv[0] && hi == ri[0]) ptr++;
        __syncthreads();
    }
}

// ---------------- Pass 2: merge + gather + matmul + softmax ----------------
__global__ __launch_bounds__(256) void topk_pass2(const float* __restrict__ ws_v,
                                                  const int* __restrict__ ws_i,
                                                  const float* __restrict__ h,
                                                  const float* __restrict__ W,
                                                  const float* __restrict__ b,
                                                  int D,
                                                  float* __restrict__ out) {
    const int tid = threadIdx.x;
    __shared__ float cv[NB * K];
    __shared__ int   ci[NB * K];
    __shared__ float rv[256];
    __shared__ int   ri[256];
    __shared__ int   sidx[16];

    // ---- merge top candidates (each source list is sorted descending) ----
    if (tid < NB) {
#pragma unroll
        for (int k = 0; k < K; ++k) { cv[tid*K + k] = ws_v[tid*16 + k]; ci[tid*K + k] = ws_i[tid*16 + k]; }
    }
    __syncthreads();
    int ptr = 0;
    for (int r = 0; r < K; ++r) {
        float hv = (tid < NB) ? cv[tid*K + ptr] : -FLT_MAX;
        int   hi = (tid < NB) ? ci[tid*K + ptr] : INT_MAX;
        rv[tid] = hv; ri[tid] = hi;
        __syncthreads();
        for (int s = 128; s > 0; s >>= 1) {
            if (tid < s && top_better(rv[tid+s], ri[tid+s], rv[tid], ri[tid])) {
                rv[tid] = rv[tid+s]; ri[tid] = ri[tid+s];
            }
            __syncthreads();
        }
        if (tid == 0) sidx[r] = ri[0];
        if (hv == rv[0] && hi == ri[0]) ptr++;
        __syncthreads();
    }

    // ---- merge bottom candidates (each source list sorted ascending) ----
    if (tid < NB) {
#pragma unroll
        for (int k = 0; k < K; ++k) { cv[tid*K + k] = ws_v[tid*16 + 8 + k]; ci[tid*K + k] = ws_i[tid*16 + 8 + k]; }
    }
    __syncthreads();
    ptr = 0;
    for (int r = 0; r < K; ++r) {
        float hv = (tid < NB) ? cv[tid*K + ptr] : FLT_MAX;
        int   hi = (tid < NB) ? ci[tid*K + ptr] : INT_MAX;
        rv[tid] = hv; ri[tid] = hi;
        __syncthreads();
        for (int s = 128; s > 0; s >>= 1) {
            if (tid < s && bot_better(rv[tid+s], ri[tid+s], rv[tid], ri[tid])) {
                rv[tid] = rv[tid+s]; ri[tid] = ri[tid+s];
            }
            __syncthreads();
        }
        if (tid == 0) sidx[8 + r] = ri[0];
        if (hv == rv[0] && hi == ri[0]) ptr++;
        __syncthreads();
    }
    __syncthreads();

    // ---- labels (harness reads whole d_out as float32) ----
    if (tid < 16) out[tid] = (tid < 8) ? 1.0f : 0.0f;

    // ---- 16 rows x (512 @ 512x2) dot products: one wave per row, 4 rows/wave ----
    const int w = tid >> 6;
    const int lane = tid & 63;
    for (int r = w; r < 16; r += 4) {
        const float* hr = h + (size_t)sidx[r] * (size_t)D;
        float s0 = 0.0f, s1 = 0.0f;
        for (int d = lane; d < D; d += 64) {
            float hv = hr[d];
            s0 += hv * W[d*2 + 0];
            s1 += hv * W[d*2 + 1];
        }
#pragma unroll
        for (int off = 32; off > 0; off >>= 1) {
            s0 += __shfl_down(s0, off, 64);
            s1 += __shfl_down(s1, off, 64);
        }
        if (lane == 0) {
            float z0 = s0 + b[0], z1 = s1 + b[1];
            float m  = fmaxf(z0, z1);
            float e0 = __expf(z0 - m), e1 = __expf(z1 - m);
            float inv = 1.0f / (e0 + e1);
            out[16 + r*2 + 0] = e0 * inv;
            out[16 + r*2 + 1] = e1 * inv;
        }
    }
}

extern "C" void kernel_launch(void* const* d_in, const int* in_sizes, int n_in,
                              void* d_out, int out_size, void* d_ws, size_t ws_size,
                              hipStream_t stream) {
    const float* h   = (const float*)d_in[0];
    const float* A   = (const float*)d_in[1];
    const float* W   = (const float*)d_in[2];
    const float* b   = (const float*)d_in[3];
    const int*   bag = (const int*)d_in[4];

    const int n = in_sizes[1] / 2;   // N = 500000 (A has N*1*2 elements)
    const int D = in_sizes[2] / 2;   // 512 (W has D*2 elements)

    float* ws_v = (float*)d_ws;
    int*   ws_i = (int*)((float*)d_ws + NB * 16);

    topk_pass1<<<NB, NT, 0, stream>>>((const float2*)A, bag, n, ws_v, ws_i);
    topk_pass2<<<1, 256, 0, stream>>>(ws_v, ws_i, h, W, b, D, (float*)d_out);
}